// Round 17
// baseline (67.529 us; speedup 1.0000x reference)
//
#include <hip/hip_runtime.h>
#include <stdint.h>

#define NROWS 8192
#define DDIM 256
#define NPIDS 5532
#define NCQ 5000
#define LCOLS 10532            // NPIDS + NCQ
#define IGNORE_IDX 5554
#define NT 83                  // ceil(10532/128)
#define LPAD (NT * 128)        // 10624
#define NSPLIT 8
#define NPARTS (NSPLIT * 2)    // 16 partial slots per row
#define PADCOLS (LPAD - LCOLS) // 92, each contributes exp2(0)=1 exactly
#define TSTEP (NSPLIT * 65536) // 524288 B between consecutive tiles of a split
#define OIM_SCALE 30.0f
#define LOG2E 1.4426950408889634f
#define LN2f 0.6931471805599453f

using f32x4 = __attribute__((ext_vector_type(4))) float;
using f32x16 = __attribute__((ext_vector_type(16))) float;
using bf16x8 = __attribute__((ext_vector_type(8))) __bf16;
using ushort8 = __attribute__((ext_vector_type(8))) unsigned short;

// ws layout (bytes)
#define WS_INBF 0u             // 8192*256*2   = 4,194,304 (frag-order bf16)
#define WS_BANK 4194304u       // 10624*256*2  = 5,439,488 (frag-order, rse-scaled)
#define WS_PARTS 9633792u      // 16*8192*4    = 524,288
#define WS_RLOGIT 10158080u    // 8192*4       = 32,768
#define WS_BLK 10190848u       // 32*2*4       = 256
#define WS_NEED 10191104u

__device__ __forceinline__ unsigned short f2bf(float f) {
  union { float f; uint32_t u; } v; v.f = f;
  uint32_t u = v.u;
  uint32_t r = (u + 0x7FFFu + ((u >> 16) & 1u)) >> 16;  // RNE
  return (unsigned short)r;
}

__device__ __forceinline__ void async16(const void* g, void* l) {
  __builtin_amdgcn_global_load_lds(
      (const __attribute__((address_space(1))) uint32_t*)g,
      (__attribute__((address_space(3))) uint32_t*)l, 16, 0, 0);
}

// ---------------------------------------------------------------------------
// prep: 32x32x16-fragment-order layouts (A operand: lane l of a frag holds
// row = l&31, k = (l>>5)*8 + j -> granule g = (R&31) + 32*((k>>3)&1)):
//   A byte(R,k) = (R>>5)*16384 + ((k>>4))*1024 + ((k>>3)&1)*512 + (R&31)*16
//   B byte(C,k) = (C>>7)*65536 + ((C>>5)&3)*16384 + ((k>>4))*1024
//                 + ((k>>3)&1)*512 + (C&31)*16
// B row C scaled by 30*rel[C]*log2e BEFORE bf16 quantization; pad rows = 0.
// Every main-loop operand transfer is ONE coalesced 1KB op.
// ---------------------------------------------------------------------------
__global__ void prep_kernel(const float* __restrict__ inputs,
                            const float* __restrict__ lut,
                            const float* __restrict__ cq,
                            const float* __restrict__ rel,
                            unsigned short* __restrict__ in2,
                            unsigned short* __restrict__ bank3) {
  const int GIN = NROWS * (DDIM / 8);   // 262144 dst granules (16B)
  const int GBK = LPAD * (DDIM / 8);    // 339968 dst granules
  const int total = GIN + GBK;
  for (int d = blockIdx.x * blockDim.x + threadIdx.x; d < total;
       d += gridDim.x * blockDim.x) {
    const float* src = nullptr;
    unsigned short* dst;
    float scale = 1.0f;
    bool zero = false;
    if (d < GIN) {
      // [rowblk 32][kstep 16][khalf 2][r5 32]
      const int v = d & 1023;
      const int g = v & 63;
      const int R = ((d >> 10) << 5) | (g & 31);
      const int c8 = ((v >> 6) << 1) | (g >> 5);
      src = inputs + R * DDIM + c8 * 8;
      dst = in2 + (size_t)d * 8;
    } else {
      const int b = d - GIN;
      // [tile][colblk 4][kstep 16][khalf 2][c5 32]
      const int w = b & 4095;
      const int v = w & 1023;
      const int g = v & 63;
      const int C = ((b >> 12) << 7) | ((w >> 10) << 5) | (g & 31);
      const int c8 = ((v >> 6) << 1) | (g >> 5);
      dst = bank3 + (size_t)b * 8;
      if (C < NPIDS) src = lut + (size_t)C * DDIM + c8 * 8;
      else if (C < LCOLS) src = cq + (size_t)(C - NPIDS) * DDIM + c8 * 8;
      else zero = true;
      if (!zero) scale = OIM_SCALE * LOG2E * rel[C];
    }
    ushort8 o = {0, 0, 0, 0, 0, 0, 0, 0};
    if (!zero) {
      const f32x4* s4 = (const f32x4*)src;
      f32x4 v0 = s4[0], v1 = s4[1];
      o[0] = f2bf(v0[0] * scale); o[1] = f2bf(v0[1] * scale);
      o[2] = f2bf(v0[2] * scale); o[3] = f2bf(v0[3] * scale);
      o[4] = f2bf(v1[0] * scale); o[5] = f2bf(v1[1] * scale);
      o[6] = f2bf(v1[2] * scale); o[7] = f2bf(v1[3] * scale);
    }
    *(ushort8*)dst = o;
  }
}

// ---------------------------------------------------------------------------
// main: fused GEMM + sum-of-exp. EXACT r10 skeleton (best: 47.4us) with the
// MFMA shape swapped 16x16x32 -> 32x32x16 (2382 vs 2075 TF ubench; halves
// MFMA instruction count at same LDS traffic -> -17% matrix-pipe time and
// less issue pressure at 2 waves/SIMD).
// 256 blocks = 1/CU, 512 thr = 8 waves (4 wrow x 2 wcol), BM=256, per-tile
// BN=128, K=256 = 4 phases of K64. A reg-persistent aR[2][16] (128 VGPR).
// B: 4 x 16KB LDS ring; per phase: STG(phase+2) -> vmcnt(4) -> s_barrier ->
// 8 ds_read_b128 -> lgkmcnt(0) -> 16 x mfma_32x32x16 (acc 2x2 f32x16).
// C/D layout (m74/m101): col=lane&31, row=(reg&3)+8*(reg>>2)+4*(lane>>5).
// Row-sums: xor-reduce masks 1..16 (32 cols within each lane-half).
// sp = bid&7 = XCD id (B slice 1.3MB L2-resident per XCD).
// ---------------------------------------------------------------------------
#define STG(ADV)                                                          \
  do {                                                                    \
    char* _d = ring + roS + (tid >> 7) * 4096 + (tid & 127) * 16;         \
    const char* _s = sgP + (tid >> 7) * 16384 + (tid & 127) * 16;         \
    async16(_s, _d);                                                      \
    async16(_s + 2048, _d + 2048);                                        \
    sgP += (ADV);                                                         \
    roS += 16384; if (roS == 65536) roS = 0;                              \
  } while (0)

#define COMP(PP)                                                          \
  do {                                                                    \
    const char* _c = rB + roN;                                            \
    bf16x8 bF[2][4];                                                      \
    _Pragma("unroll") for (int _nb = 0; _nb < 2; ++_nb)                   \
      _Pragma("unroll") for (int _ks = 0; _ks < 4; ++_ks)                 \
        bF[_nb][_ks] = *(const bf16x8*)(_c + _nb * 4096 + _ks * 1024);    \
    asm volatile("s_waitcnt lgkmcnt(0)" ::: "memory");                    \
    __builtin_amdgcn_sched_barrier(0);                                    \
    __builtin_amdgcn_s_setprio(1);                                        \
    _Pragma("unroll") for (int _ks = 0; _ks < 4; ++_ks)                   \
      _Pragma("unroll") for (int _mi = 0; _mi < 2; ++_mi)                 \
        _Pragma("unroll") for (int _nb = 0; _nb < 2; ++_nb)               \
          acc[_mi][_nb] = __builtin_amdgcn_mfma_f32_32x32x16_bf16(        \
              aR[_mi][(PP) * 4 + _ks], bF[_nb][_ks],                      \
              ((PP) == 0 && _ks == 0) ? vzero : acc[_mi][_nb], 0, 0, 0);  \
    __builtin_amdgcn_s_setprio(0);                                        \
    roN += 16384; if (roN == 65536) roN = 0;                              \
  } while (0)

#define VMB(VMN)                                                          \
  do {                                                                    \
    asm volatile("s_waitcnt vmcnt(" #VMN ")" ::: "memory");               \
    asm volatile("s_barrier" ::: "memory");                               \
  } while (0)

#define EPILOG()                                                          \
  do {                                                                    \
    _Pragma("unroll") for (int _mi = 0; _mi < 2; ++_mi)                   \
      _Pragma("unroll") for (int _nb = 0; _nb < 2; ++_nb)                 \
        _Pragma("unroll") for (int _r = 0; _r < 16; ++_r)                 \
          se[_mi][_r] += __builtin_amdgcn_exp2f(acc[_mi][_nb][_r]);       \
  } while (0)

__global__ __launch_bounds__(512, 1) void oim_main_kernel(
    const unsigned short* __restrict__ in2,
    const unsigned short* __restrict__ bank3,
    float* __restrict__ parts) {
  extern __shared__ char ring[];  // 65536 = 4 slots x 16KB
  const int tid = threadIdx.x;
  const int lane = tid & 63;
  const int wv = tid >> 6;    // 0..7
  const int wrow = wv >> 1;   // 0..3
  const int wcol = wv & 1;    // 0..1
  const int hb = lane >> 5;   // 0..1 (lane half)

  const int bid = blockIdx.x;
  const int sp = bid & 7;     // == XCD id under round-robin dispatch
  const int bm = bid >> 3;    // 0..31 (256-row blocks)
  const int ntiles = (sp < 3) ? 11 : 10;  // 3*11 + 5*10 = 83

  // ---- A fragments -> registers (32 coalesced dwordx4, once) ----
  // aR[mi][kk]: rows (bm*256 + wrow*64 + mi*32 .. +31), ksteps kk*16..+15
  bf16x8 aR[2][16];
  {
    const char* ab =
        (const char*)in2 + (size_t)(bm * 8 + wrow * 2) * 16384 + lane * 16;
#pragma unroll
    for (int mi = 0; mi < 2; ++mi)
#pragma unroll
      for (int kk = 0; kk < 16; ++kk)
        aR[mi][kk] = *(const bf16x8*)(ab + mi * 16384 + kk * 1024);
  }
  const int rowb0 = bm * 256 + wrow * 64;

  asm volatile("" ::: "memory");  // pin: A-loads precede staging (vmcnt order)

  // staging: 16KB/phase; slot = [colblk 4 x 4KB][kstep 4 x 1KB][g 64].
  // src per phase pp: tile + colblk*16384 + pp*4096 + within.
  const char* sgT = (const char*)bank3 + (size_t)sp * 65536;
  // prologue: stage phases 0,1 -> slots 0,1 (4 ops in flight)
#pragma unroll
  for (int p = 0; p < 2; ++p) {
    char* d = ring + p * 16384 + (tid >> 7) * 4096 + (tid & 127) * 16;
    const char* s = sgT + (tid >> 7) * 16384 + p * 4096 + (tid & 127) * 16;
    async16(s, d);
    async16(s + 2048, d + 2048);
  }
  const char* sgP = sgT + 8192;   // source base of stage phase 2
  int roS = 32768;                // slot of stage phase 2
  int roN = 0;                    // consume slot

  // per-wave LDS read base (its wcol 64-col strip = colblks 2wcol..2wcol+1)
  const char* rB = ring + wcol * 8192 + lane * 16;

  const f32x16 vzero = {0.f, 0.f, 0.f, 0.f, 0.f, 0.f, 0.f, 0.f,
                        0.f, 0.f, 0.f, 0.f, 0.f, 0.f, 0.f, 0.f};
  f32x16 acc[2][2];
  float se[2][16];
#pragma unroll
  for (int a = 0; a < 2; ++a)
#pragma unroll
    for (int b = 0; b < 16; ++b) se[a][b] = 0.f;

  for (int t = 0; t < ntiles - 1; ++t) {
    STG(4096);           VMB(4); COMP(0);
    STG(TSTEP - 12288);  VMB(4); COMP(1);
    STG(4096);           VMB(4); COMP(2);
    STG(4096);           VMB(4); COMP(3);
    EPILOG();  // pure exp2+add (B pre-scaled by rse; pad cols -> +1.0)
  }
  // ---- last tile: stages NQ-2, NQ-1 then drain ----
  STG(4096); VMB(4); COMP(0);
  STG(4096); VMB(4); COMP(1);
  VMB(2); COMP(2);
  VMB(0); COMP(3);
  EPILOG();

  // reduce across the 32 column-lanes of each half (cols of the row)
#pragma unroll
  for (int mi = 0; mi < 2; ++mi)
#pragma unroll
    for (int r = 0; r < 16; ++r) {
      float v = se[mi][r];
      v += __shfl_xor(v, 1);
      v += __shfl_xor(v, 2);
      v += __shfl_xor(v, 4);
      v += __shfl_xor(v, 8);
      v += __shfl_xor(v, 16);
      se[mi][r] = v;
    }
  if ((lane & 31) == 0) {
    const int part = sp * 2 + wcol;  // deterministic partial slot, 0..15
    // reg r -> row (r&3) + 8*(r>>2) + 4*hb within the 32-row block
#pragma unroll
    for (int mi = 0; mi < 2; ++mi)
#pragma unroll
      for (int q = 0; q < 4; ++q) {
        const int row = rowb0 + mi * 32 + hb * 4 + q * 8;
        f32x4 o = {se[mi][q * 4], se[mi][q * 4 + 1],
                   se[mi][q * 4 + 2], se[mi][q * 4 + 3]};
        *(f32x4*)(parts + (size_t)part * NROWS + row) = o;
      }
  }
}

// ---------------------------------------------------------------------------
// exact fp32 label logit: one wave per row, gather bank row by label.
// ---------------------------------------------------------------------------
__global__ void label_logit_kernel(const float* __restrict__ inputs,
                                   const int* __restrict__ label,
                                   const float* __restrict__ lut,
                                   const float* __restrict__ cq,
                                   const float* __restrict__ rel,
                                   float* __restrict__ rowlogit) {
  const int lane = threadIdx.x & 63;
  const int wv = threadIdx.x >> 6;
  const int row = blockIdx.x * 4 + wv;
  if (row >= NROWS) return;
  const int l = label[row];
  float out = 0.0f;
  if (l != IGNORE_IDX && l >= 0 && l < LCOLS) {
    const float* bk = (l < NPIDS) ? (lut + (size_t)l * DDIM)
                                  : (cq + (size_t)(l - NPIDS) * DDIM);
    f32x4 a = *(const f32x4*)(inputs + (size_t)row * DDIM + lane * 4);
    f32x4 b = *(const f32x4*)(bk + lane * 4);
    float d = a[0] * b[0] + a[1] * b[1] + a[2] * b[2] + a[3] * b[3];
#pragma unroll
    for (int m = 1; m < 64; m <<= 1) d += __shfl_xor(d, m);
    out = OIM_SCALE * rel[l] * d;
  }
  if (lane == 0) rowlogit[row] = out;
}

// ---------------------------------------------------------------------------
// reduce1: 32 blocks x 256 threads, one row per thread.
// tot = sum(parts) - PADCOLS; s = ln2*log2(tot) - rowlogit for valid rows.
// ---------------------------------------------------------------------------
__global__ void reduce1_kernel(const float* __restrict__ parts,
                               const float* __restrict__ rowlogit,
                               const int* __restrict__ label,
                               float* __restrict__ blk) {
  const int r = blockIdx.x * 256 + threadIdx.x;
  float s = 0.0f, c = 0.0f;
  if (label[r] != IGNORE_IDX) {
    float tot = 0.0f;
#pragma unroll
    for (int p = 0; p < NPARTS; ++p) tot += parts[p * NROWS + r];
    tot -= (float)PADCOLS;
    s = LN2f * __builtin_log2f(tot) - rowlogit[r];
    c = 1.0f;
  }
#pragma unroll
  for (int m = 1; m < 64; m <<= 1) {
    s += __shfl_xor(s, m);
    c += __shfl_xor(c, m);
  }
  __shared__ float ss[4], sc[4];
  const int wv = threadIdx.x >> 6, lane = threadIdx.x & 63;
  if (lane == 0) { ss[wv] = s; sc[wv] = c; }
  __syncthreads();
  if (threadIdx.x == 0) {
    blk[blockIdx.x * 2 + 0] = ss[0] + ss[1] + ss[2] + ss[3];
    blk[blockIdx.x * 2 + 1] = sc[0] + sc[1] + sc[2] + sc[3];
  }
}

__global__ void reduce2_kernel(const float* __restrict__ blk,
                               float* __restrict__ out) {
  const int lane = threadIdx.x;
  float s = (lane < 32) ? blk[lane * 2 + 0] : 0.0f;
  float c = (lane < 32) ? blk[lane * 2 + 1] : 0.0f;
#pragma unroll
  for (int m = 1; m < 32; m <<= 1) {
    s += __shfl_xor(s, m);
    c += __shfl_xor(c, m);
  }
  if (lane == 0) out[0] = s / fmaxf(c, 1.0f);
}

extern "C" void kernel_launch(void* const* d_in, const int* in_sizes, int n_in,
                              void* d_out, int out_size, void* d_ws,
                              size_t ws_size, hipStream_t stream) {
  const float* inputs = (const float*)d_in[0];
  const int* label = (const int*)d_in[1];
  // d_in[2] = ious (unused by the reference loss)
  const float* lut = (const float*)d_in[3];
  const float* cq = (const float*)d_in[4];
  const float* rel = (const float*)d_in[5];
  float* out = (float*)d_out;
  char* ws = (char*)d_ws;
  if (ws_size < WS_NEED) return;

  unsigned short* in2 = (unsigned short*)(ws + WS_INBF);
  unsigned short* bank3 = (unsigned short*)(ws + WS_BANK);
  float* parts = (float*)(ws + WS_PARTS);
  float* rowlogit = (float*)(ws + WS_RLOGIT);
  float* blk = (float*)(ws + WS_BLK);

  hipFuncSetAttribute((const void*)oim_main_kernel,
                      hipFuncAttributeMaxDynamicSharedMemorySize, 65536);

  prep_kernel<<<dim3(1024), dim3(256), 0, stream>>>(inputs, lut, cq, rel,
                                                    in2, bank3);
  label_logit_kernel<<<dim3(2048), dim3(256), 0, stream>>>(inputs, label, lut,
                                                           cq, rel, rowlogit);
  oim_main_kernel<<<dim3(256), dim3(512), 65536, stream>>>(in2, bank3, parts);
  reduce1_kernel<<<dim3(32), dim3(256), 0, stream>>>(parts, rowlogit, label,
                                                     blk);
  reduce2_kernel<<<dim3(1), dim3(64), 0, stream>>>(blk, out);
}

// Round 18
// 57.251 us; speedup vs baseline: 1.1795x; 1.1795x over previous
//
#include <hip/hip_runtime.h>
#include <stdint.h>

#define NROWS 8192
#define DDIM 256
#define NPIDS 5532
#define NCQ 5000
#define LCOLS 10532            // NPIDS + NCQ
#define IGNORE_IDX 5554
#define NT 83                  // ceil(10532/128)
#define LPAD (NT * 128)        // 10624
#define NSPLIT 8
#define NPARTS (NSPLIT * 2)    // 16 partial slots per row
#define PADCOLS (LPAD - LCOLS) // 92, each contributes exp2(0)=1 exactly
#define TSTEP (NSPLIT * 65536) // 524288 B between consecutive tiles of a split
#define OIM_SCALE 30.0f
#define LOG2E 1.4426950408889634f
#define LN2f 0.6931471805599453f

using f32x4 = __attribute__((ext_vector_type(4))) float;
using bf16x8 = __attribute__((ext_vector_type(8))) __bf16;
using ushort8 = __attribute__((ext_vector_type(8))) unsigned short;

// ws layout (bytes)
#define WS_INBF 0u             // 8192*256*2   = 4,194,304 (frag-order bf16)
#define WS_BANK 4194304u       // 10624*256*2  = 5,439,488 (frag-order, rse-scaled)
#define WS_PARTS 9633792u      // 16*8192*4    = 524,288
#define WS_RLOGIT 10158080u    // 8192*4       = 32,768
#define WS_BLK 10190848u       // 32*2*4       = 256
#define WS_NEED 10191104u

__device__ __forceinline__ unsigned short f2bf(float f) {
  union { float f; uint32_t u; } v; v.f = f;
  uint32_t u = v.u;
  uint32_t r = (u + 0x7FFFu + ((u >> 16) & 1u)) >> 16;  // RNE
  return (unsigned short)r;
}

__device__ __forceinline__ void async16(const void* g, void* l) {
  __builtin_amdgcn_global_load_lds(
      (const __attribute__((address_space(1))) uint32_t*)g,
      (__attribute__((address_space(3))) uint32_t*)l, 16, 0, 0);
}

// ---------------------------------------------------------------------------
// prep + label fused. 2048 blocks x 256 threads.
// Part 1 (label): each block's 4 waves compute the exact fp32 label logit for
// rows bid*4 .. bid*4+3 (coalesced 1KB row reads, shuffle reduce).
// Part 2 (prep): grid-stride over conversion granules — store A and B in MFMA
// fragment-consumption order so every main-loop operand transfer is ONE
// coalesced 1KB op:
//   A byte(R,k)  = (R>>4)*8192 + (k>>5)*1024 + ((k>>3)&3)*256 + (R&15)*16
//   B byte(R,k)  = (R>>7)*65536 + ((R>>4)&7)*8192 + (k>>5)*1024
//                  + ((k>>3)&3)*256 + (R&15)*16
// B row R scaled by 30*rel[R]*log2e BEFORE bf16 quantization; pad rows = 0.
// ---------------------------------------------------------------------------
__global__ void prep_label_kernel(const float* __restrict__ inputs,
                                  const int* __restrict__ label,
                                  const float* __restrict__ lut,
                                  const float* __restrict__ cq,
                                  const float* __restrict__ rel,
                                  unsigned short* __restrict__ in2,
                                  unsigned short* __restrict__ bank3,
                                  float* __restrict__ rowlogit) {
  // ---- label logit: one wave per row ----
  {
    const int lane = threadIdx.x & 63;
    const int wvl = threadIdx.x >> 6;
    const int row = blockIdx.x * 4 + wvl;
    const int l = label[row];
    float out = 0.0f;
    if (l != IGNORE_IDX && l >= 0 && l < LCOLS) {
      const float* bk = (l < NPIDS) ? (lut + (size_t)l * DDIM)
                                    : (cq + (size_t)(l - NPIDS) * DDIM);
      f32x4 a = *(const f32x4*)(inputs + (size_t)row * DDIM + lane * 4);
      f32x4 b = *(const f32x4*)(bk + lane * 4);
      float d = a[0] * b[0] + a[1] * b[1] + a[2] * b[2] + a[3] * b[3];
#pragma unroll
      for (int m = 1; m < 64; m <<= 1) d += __shfl_xor(d, m);
      out = OIM_SCALE * rel[l] * d;
    }
    if (lane == 0) rowlogit[row] = out;
  }
  // ---- conversion granules, grid-stride ----
  const int GIN = NROWS * (DDIM / 8);   // 262144 dst granules (16B)
  const int GBK = LPAD * (DDIM / 8);    // 339968 dst granules
  const int total = GIN + GBK;
  for (int d = blockIdx.x * blockDim.x + threadIdx.x; d < total;
       d += gridDim.x * blockDim.x) {
    const float* src = nullptr;
    unsigned short* dst;
    float scale = 1.0f;
    bool zero = false;
    if (d < GIN) {
      const int R = ((d >> 9) << 4) | (d & 15);
      const int c8 = (((d >> 6) & 7) << 2) | ((d >> 4) & 3);
      src = inputs + R * DDIM + c8 * 8;
      dst = in2 + (size_t)d * 8;
    } else {
      const int b = d - GIN;
      const int R = ((b >> 12) << 7) | (((b >> 9) & 7) << 4) | (b & 15);
      const int c8 = (((b >> 6) & 7) << 2) | ((b >> 4) & 3);
      dst = bank3 + (size_t)b * 8;
      if (R < NPIDS) src = lut + (size_t)R * DDIM + c8 * 8;
      else if (R < LCOLS) src = cq + (size_t)(R - NPIDS) * DDIM + c8 * 8;
      else zero = true;
      if (!zero) scale = OIM_SCALE * LOG2E * rel[R];
    }
    ushort8 o = {0, 0, 0, 0, 0, 0, 0, 0};
    if (!zero) {
      const f32x4* s4 = (const f32x4*)src;
      f32x4 v0 = s4[0], v1 = s4[1];
      o[0] = f2bf(v0[0] * scale); o[1] = f2bf(v0[1] * scale);
      o[2] = f2bf(v0[2] * scale); o[3] = f2bf(v0[3] * scale);
      o[4] = f2bf(v1[0] * scale); o[5] = f2bf(v1[1] * scale);
      o[6] = f2bf(v1[2] * scale); o[7] = f2bf(v1[3] * scale);
    }
    *(ushort8*)dst = o;
  }
}

// ---------------------------------------------------------------------------
// main: fused GEMM + sum-of-exp. Verbatim round-10 structure (the measured
// best: 47.4us, VGPR 128, zero bank conflicts, zero spill).
// 256 blocks = 1/CU, 512 thr = 8 waves (4 wrow x 2 wcol), BM=256, per-tile
// BN=128, K=256 = 4 phases of K64. A reg-persistent aR[4][8] (128 VGPR).
// B: 4 x 16KB LDS ring, staged cooperatively (2 async16/thread/phase),
// depth-2 prefetch, counted vmcnt(4) + one raw s_barrier per phase.
// Staging demand = 64 B/MFMA (the r9->r10 lever: the ~33% wall tracked
// staged-bytes-per-MFMA). sp = bid&7 = XCD id (B slice L2-resident).
// ---------------------------------------------------------------------------
#define STG(PP)                                                           \
  do {                                                                    \
    char* _d = dT + (((PP) + 2) & 3) * 16384;                             \
    async16(sgP, _d);                                                     \
    async16(sgP + 32768, _d + 8192);                                      \
    sgP += ((PP) == 1) ? (TSTEP - 6144) : 2048;                           \
  } while (0)

#define PHASE(PP, VMN)                                                    \
  do {                                                                    \
    asm volatile("s_waitcnt vmcnt(" #VMN ")" ::: "memory");               \
    asm volatile("s_barrier" ::: "memory");                               \
    const char* _c = rB + (PP) * 16384;                                   \
    bf16x8 bF[4][2];                                                      \
    _Pragma("unroll") for (int _ni = 0; _ni < 4; ++_ni)                   \
      _Pragma("unroll") for (int _kl = 0; _kl < 2; ++_kl)                 \
        bF[_ni][_kl] = *(const bf16x8*)(_c + _ni * 2048 + _kl * 1024);    \
    asm volatile("s_waitcnt lgkmcnt(0)" ::: "memory");                    \
    __builtin_amdgcn_sched_barrier(0);                                    \
    __builtin_amdgcn_s_setprio(1);                                        \
    _Pragma("unroll") for (int _kl = 0; _kl < 2; ++_kl)                   \
      _Pragma("unroll") for (int _mi = 0; _mi < 4; ++_mi)                 \
        _Pragma("unroll") for (int _ni = 0; _ni < 4; ++_ni)               \
          acc[_mi][_ni] = __builtin_amdgcn_mfma_f32_16x16x32_bf16(        \
              aR[_mi][(PP) * 2 + _kl], bF[_ni][_kl],                      \
              ((PP) == 0 && _kl == 0) ? vzero : acc[_mi][_ni], 0, 0, 0);  \
    __builtin_amdgcn_s_setprio(0);                                        \
  } while (0)

__global__ __launch_bounds__(512, 2) void oim_main_kernel(
    const unsigned short* __restrict__ in2,
    const unsigned short* __restrict__ bank3,
    float* __restrict__ parts) {
  extern __shared__ char ring[];  // 65536 = 4 slots x 16KB
  const int tid = threadIdx.x;
  const int lane = tid & 63;
  const int wv = tid >> 6;    // 0..7
  const int wrow = wv >> 1;   // 0..3
  const int wcol = wv & 1;    // 0..1
  const int ql = lane & 15;
  const int h = lane >> 4;    // 0..3

  const int bid = blockIdx.x;
  const int sp = bid & 7;     // == XCD id under round-robin dispatch
  const int bm = bid >> 3;    // 0..31 (256-row blocks)
  const int ntiles = (sp < 3) ? 11 : 10;  // 3*11 + 5*10 = 83

  // ---- A fragments -> registers (32 coalesced dwordx4, once) ----
  bf16x8 aR[4][8];
  {
    const char* ab =
        (const char*)in2 + (size_t)(bm * 16 + wrow * 4) * 8192 + lane * 16;
#pragma unroll
    for (int mi = 0; mi < 4; ++mi)
#pragma unroll
      for (int kk = 0; kk < 8; ++kk)
        aR[mi][kk] = *(const bf16x8*)(ab + mi * 8192 + kk * 1024);
  }
  const int rowb = bm * 256 + wrow * 64 + h * 4;

  asm volatile("" ::: "memory");  // pin: A-loads precede staging (vmcnt order)

  // staging: per-thread src/dst. LDS slot layout = [colblk 8][kkl 2][lane]:
  //   dst half0 o=tid*16 <-> colblk=tid>>7, within=(tid&127)*16; half1 +8192
  //   src = tile + colblk*8192 + pp*2048 + within   (second half +32768)
  const char* sgT = (const char*)bank3 + (size_t)sp * 65536 +
                    (tid >> 7) * 8192 + (tid & 127) * 16;
  char* dT = ring + tid * 16;

  // prologue: stage (tile0,pp0)->slot0, (tile0,pp1)->slot1
  async16(sgT, dT);
  async16(sgT + 32768, dT + 8192);
  asm volatile("" ::: "memory");
  async16(sgT + 2048, dT + 16384);
  async16(sgT + 2048 + 32768, dT + 16384 + 8192);
  asm volatile("" ::: "memory");
  const char* sgP = sgT + 4096;  // next stage: (tile0, pp2)

  // per-wave LDS read base (its wcol 64-col strip)
  const char* rB = ring + (wcol * 4) * 2048 + lane * 16;

  const f32x4 vzero = {0.f, 0.f, 0.f, 0.f};
  f32x4 acc[4][4];
  float se[4][4];
#pragma unroll
  for (int a = 0; a < 4; ++a)
#pragma unroll
    for (int b = 0; b < 4; ++b) se[a][b] = 0.f;

  for (int t = 0; t < ntiles - 1; ++t) {
    STG(0); PHASE(0, 4);
    STG(1); PHASE(1, 4);
    STG(2); PHASE(2, 4);
    STG(3); PHASE(3, 4);
    // tile epilogue: pure exp2+add (B pre-scaled by rse; pad cols -> +1.0)
#pragma unroll
    for (int mi = 0; mi < 4; ++mi)
#pragma unroll
      for (int ni = 0; ni < 4; ++ni)
#pragma unroll
        for (int r = 0; r < 4; ++r)
          se[mi][r] += __builtin_amdgcn_exp2f(acc[mi][ni][r]);
  }
  // ---- last tile: stages for its first two phases, then drain ----
  STG(0); PHASE(0, 4);
  STG(1); PHASE(1, 4);
  PHASE(2, 2);
  PHASE(3, 0);
#pragma unroll
  for (int mi = 0; mi < 4; ++mi)
#pragma unroll
    for (int ni = 0; ni < 4; ++ni)
#pragma unroll
      for (int r = 0; r < 4; ++r)
        se[mi][r] += __builtin_amdgcn_exp2f(acc[mi][ni][r]);

  // reduce across the 16 column-lanes (ql) of each row group
#pragma unroll
  for (int mi = 0; mi < 4; ++mi)
#pragma unroll
    for (int r = 0; r < 4; ++r) {
      float v = se[mi][r];
      v += __shfl_xor(v, 1);
      v += __shfl_xor(v, 2);
      v += __shfl_xor(v, 4);
      v += __shfl_xor(v, 8);
      se[mi][r] = v;
    }
  if (ql == 0) {
    const int part = sp * 2 + wcol;  // deterministic partial slot, 0..15
#pragma unroll
    for (int mi = 0; mi < 4; ++mi) {
      f32x4 o = {se[mi][0], se[mi][1], se[mi][2], se[mi][3]};
      *(f32x4*)(parts + (size_t)part * NROWS + rowb + mi * 16) = o;
    }
  }
}

// ---------------------------------------------------------------------------
// reduce1: 32 blocks x 256 threads, one row per thread.
// tot = sum(parts) - PADCOLS; s = ln2*log2(tot) - rowlogit for valid rows.
// ---------------------------------------------------------------------------
__global__ void reduce1_kernel(const float* __restrict__ parts,
                               const float* __restrict__ rowlogit,
                               const int* __restrict__ label,
                               float* __restrict__ blk) {
  const int r = blockIdx.x * 256 + threadIdx.x;
  float s = 0.0f, c = 0.0f;
  if (label[r] != IGNORE_IDX) {
    float tot = 0.0f;
#pragma unroll
    for (int p = 0; p < NPARTS; ++p) tot += parts[p * NROWS + r];
    tot -= (float)PADCOLS;
    s = LN2f * __builtin_log2f(tot) - rowlogit[r];
    c = 1.0f;
  }
#pragma unroll
  for (int m = 1; m < 64; m <<= 1) {
    s += __shfl_xor(s, m);
    c += __shfl_xor(c, m);
  }
  __shared__ float ss[4], sc[4];
  const int wv = threadIdx.x >> 6, lane = threadIdx.x & 63;
  if (lane == 0) { ss[wv] = s; sc[wv] = c; }
  __syncthreads();
  if (threadIdx.x == 0) {
    blk[blockIdx.x * 2 + 0] = ss[0] + ss[1] + ss[2] + ss[3];
    blk[blockIdx.x * 2 + 1] = sc[0] + sc[1] + sc[2] + sc[3];
  }
}

__global__ void reduce2_kernel(const float* __restrict__ blk,
                               float* __restrict__ out) {
  const int lane = threadIdx.x;
  float s = (lane < 32) ? blk[lane * 2 + 0] : 0.0f;
  float c = (lane < 32) ? blk[lane * 2 + 1] : 0.0f;
#pragma unroll
  for (int m = 1; m < 32; m <<= 1) {
    s += __shfl_xor(s, m);
    c += __shfl_xor(c, m);
  }
  if (lane == 0) out[0] = s / fmaxf(c, 1.0f);
}

extern "C" void kernel_launch(void* const* d_in, const int* in_sizes, int n_in,
                              void* d_out, int out_size, void* d_ws,
                              size_t ws_size, hipStream_t stream) {
  const float* inputs = (const float*)d_in[0];
  const int* label = (const int*)d_in[1];
  // d_in[2] = ious (unused by the reference loss)
  const float* lut = (const float*)d_in[3];
  const float* cq = (const float*)d_in[4];
  const float* rel = (const float*)d_in[5];
  float* out = (float*)d_out;
  char* ws = (char*)d_ws;
  if (ws_size < WS_NEED) return;

  unsigned short* in2 = (unsigned short*)(ws + WS_INBF);
  unsigned short* bank3 = (unsigned short*)(ws + WS_BANK);
  float* parts = (float*)(ws + WS_PARTS);
  float* rowlogit = (float*)(ws + WS_RLOGIT);
  float* blk = (float*)(ws + WS_BLK);

  hipFuncSetAttribute((const void*)oim_main_kernel,
                      hipFuncAttributeMaxDynamicSharedMemorySize, 65536);

  prep_label_kernel<<<dim3(2048), dim3(256), 0, stream>>>(
      inputs, label, lut, cq, rel, in2, bank3, rowlogit);
  oim_main_kernel<<<dim3(256), dim3(512), 65536, stream>>>(in2, bank3, parts);
  reduce1_kernel<<<dim3(32), dim3(256), 0, stream>>>(parts, rowlogit, label,
                                                     blk);
  reduce2_kernel<<<dim3(1), dim3(64), 0, stream>>>(blk, out);
}

// Round 19
// 54.493 us; speedup vs baseline: 1.2392x; 1.0506x over previous
//
#include <hip/hip_runtime.h>
#include <stdint.h>

#define NROWS 8192
#define DDIM 256
#define NPIDS 5532
#define NCQ 5000
#define LCOLS 10532            // NPIDS + NCQ
#define IGNORE_IDX 5554
#define NT 83                  // ceil(10532/128)
#define LPAD (NT * 128)        // 10624
#define NSPLIT 8
#define NPARTS (NSPLIT * 2)    // 16 partial slots per row
#define PADCOLS (LPAD - LCOLS) // 92, each contributes exp2(0)=1 exactly
#define BTILE 32768            // fp8 B tile bytes (128 cols x 256 k)
#define TSTEP (NSPLIT * BTILE) // 262144 B between consecutive tiles of a split
#define OIM_SCALE 30.0f
#define LOG2E 1.4426950408889634f
#define LN2f 0.6931471805599453f
#define SA 4.0f                // A pre-scale (folded out of B's scale)

using f32x4 = __attribute__((ext_vector_type(4))) float;
using i64x2 = __attribute__((ext_vector_type(2))) long;
using uchar16 = __attribute__((ext_vector_type(16))) unsigned char;

// ws layout (bytes)
#define WS_INF8 0u             // 8192*256*1   = 2,097,152 (frag-order fp8)
#define WS_BANK 2097152u       // 10624*256*1  = 2,719,744 (frag-order, scaled)
#define WS_PARTS 4816896u      // 16*8192*4    = 524,288
#define WS_RLOGIT 5341184u     // 8192*4       = 32,768
#define WS_BLK 5373952u        // 32*2*4       = 256
#define WS_NEED 5374208u

// float -> OCP e4m3fn, RNE, clamp to +-448 (no NaN emitted)
__device__ __forceinline__ unsigned char f2e4m3(float x) {
  union { float f; uint32_t u; } v; v.f = x;
  const uint32_t s = (v.u >> 24) & 0x80u;
  const int eb = (int)((v.u >> 23) & 0xFFu);
  const uint32_t m = v.u & 0x7FFFFFu;
  const int e = eb - 127;
  if (eb == 255 || e >= 9) return (unsigned char)(s | 0x7Eu);  // clamp 448
  if (e >= -6) {
    uint32_t keep = m >> 20;
    const uint32_t rest = m & 0xFFFFFu;
    keep += (rest > 0x80000u) || (rest == 0x80000u && (keep & 1u));
    uint32_t ee = (uint32_t)(e + 7);
    if (keep == 8u) { keep = 0u; ee += 1u; }
    if (ee > 15u || (ee == 15u && keep == 7u))
      return (unsigned char)(s | 0x7Eu);
    return (unsigned char)(s | (ee << 3) | keep);
  }
  if (e < -10) return (unsigned char)s;
  const int sh = 14 - e;  // 23 - (e + 9)
  const uint32_t full = 0x800000u | m;
  uint32_t q = full >> sh;
  const uint32_t rem = full & ((1u << sh) - 1u);
  const uint32_t half = 1u << (sh - 1);
  q += (rem > half) || (rem == half && (q & 1u));
  if (q >= 8u) return (unsigned char)(s | 8u);  // -> min normal 2^-6
  return (unsigned char)(s | q);
}

__device__ __forceinline__ void async16(const void* g, void* l) {
  __builtin_amdgcn_global_load_lds(
      (const __attribute__((address_space(1))) uint32_t*)g,
      (__attribute__((address_space(3))) uint32_t*)l, 16, 0, 0);
}

// ---------------------------------------------------------------------------
// prep + label fused. 2048 blocks x 256 threads.
// Part 1 (label): exact fp32 label logit, one wave per row (unchanged).
// Part 2 (prep): fp8 e4m3 conversion into MFMA fragment-consumption order.
// 16B granule = one lane's fragment PAIR (kl=0 bytes 0-7, kl=1 bytes 8-15)
// for v_mfma_f32_16x16x32_fp8_fp8 (k-map = bf16 16x16x32: lane = r16+16*kg,
// k = kg*8+j):
//   A byte(R,k) = (R>>4)*4096 + (k>>6)*1024 + L*16 + ((k>>5)&1)*8 + (k&7)
//   B byte(C,k) = (C>>7)*32768 + ((C>>4)&7)*4096 + (k>>6)*1024 + L*16 + ...
//   where L = (x&15) | (((k>>3)&3)<<4)
// A scaled by SA=4; B row C scaled by 30*rel[C]*log2e/SA (pad rows = 0).
// ---------------------------------------------------------------------------
__global__ void prep_label_kernel(const float* __restrict__ inputs,
                                  const int* __restrict__ label,
                                  const float* __restrict__ lut,
                                  const float* __restrict__ cq,
                                  const float* __restrict__ rel,
                                  unsigned char* __restrict__ inf8,
                                  unsigned char* __restrict__ bank8,
                                  float* __restrict__ rowlogit) {
  // ---- label logit: one wave per row ----
  {
    const int lane = threadIdx.x & 63;
    const int wvl = threadIdx.x >> 6;
    const int row = blockIdx.x * 4 + wvl;
    const int l = label[row];
    float out = 0.0f;
    if (l != IGNORE_IDX && l >= 0 && l < LCOLS) {
      const float* bk = (l < NPIDS) ? (lut + (size_t)l * DDIM)
                                    : (cq + (size_t)(l - NPIDS) * DDIM);
      f32x4 a = *(const f32x4*)(inputs + (size_t)row * DDIM + lane * 4);
      f32x4 b = *(const f32x4*)(bk + lane * 4);
      float d = a[0] * b[0] + a[1] * b[1] + a[2] * b[2] + a[3] * b[3];
#pragma unroll
      for (int m = 1; m < 64; m <<= 1) d += __shfl_xor(d, m);
      out = OIM_SCALE * rel[l] * d;
    }
    if (lane == 0) rowlogit[row] = out;
  }
  // ---- conversion granules (16B each), grid-stride ----
  const int GIN = NROWS * (DDIM / 16);   // 131072 granules
  const int GBK = LPAD * (DDIM / 16);    // 169984 granules
  const int total = GIN + GBK;
  for (int d = blockIdx.x * blockDim.x + threadIdx.x; d < total;
       d += gridDim.x * blockDim.x) {
    const float* src = nullptr;  // points at 8 floats (kl=0); kl=1 at +32
    unsigned char* dst;
    float scale = 1.0f;
    bool zero = false;
    if (d < GIN) {
      const int rest = d & 255;
      const int L = rest & 63;
      const int R = ((d >> 8) << 4) | (L & 15);
      const int k0 = ((rest >> 6) << 6) | ((L >> 4) << 3);
      src = inputs + (size_t)R * DDIM + k0;
      dst = inf8 + (size_t)d * 16;
      scale = SA;
    } else {
      const int b = d - GIN;
      const int rest = b & 2047;
      const int rest2 = rest & 255;
      const int L = rest2 & 63;
      const int C = ((b >> 11) << 7) | (((rest >> 8) & 7) << 4) | (L & 15);
      const int k0 = ((rest2 >> 6) << 6) | ((L >> 4) << 3);
      dst = bank8 + (size_t)b * 16;
      if (C < NPIDS) src = lut + (size_t)C * DDIM + k0;
      else if (C < LCOLS) src = cq + (size_t)(C - NPIDS) * DDIM + k0;
      else zero = true;
      if (!zero) scale = OIM_SCALE * LOG2E * rel[C] * (1.0f / SA);
    }
    uchar16 o = {0};
    if (!zero) {
      const f32x4* s4 = (const f32x4*)src;
      f32x4 u0 = s4[0], u1 = s4[1];        // kl = 0 (k0 .. k0+7)
      f32x4 w0 = s4[8], w1 = s4[9];        // kl = 1 (k0+32 .. k0+39)
#pragma unroll
      for (int j = 0; j < 4; ++j) {
        o[j] = f2e4m3(u0[j] * scale);
        o[j + 4] = f2e4m3(u1[j] * scale);
        o[j + 8] = f2e4m3(w0[j] * scale);
        o[j + 12] = f2e4m3(w1[j] * scale);
      }
    }
    *(uchar16*)dst = o;
  }
}

// ---------------------------------------------------------------------------
// main: fused GEMM + sum-of-exp, r10 structure with fp8 e4m3 operands.
// MFMA count/time unchanged (fp8 16x16x32 = bf16 rate) but every other term
// halves: ds_read 32 (vs 64) b128/CU/phase, staging 8KB/phase (1 async16 per
// thread), A-prologue 16 loads, aR 64 VGPR. Ring 4 x 8KB = 32KB LDS.
// 256 blocks = 1/CU, 512 thr = 8 waves (4 wrow x 2 wcol), BM=256, BN=128,
// K=256 = 4 phases; steady `s_waitcnt vmcnt(2)` + one raw s_barrier/phase.
// sp = bid&7 = XCD id (B slice 0.65MB L2-resident per XCD).
// ---------------------------------------------------------------------------
#define STG(ADV)                                                          \
  do {                                                                    \
    async16(sgP + (tid >> 6) * 4096 + (tid & 63) * 16,                    \
            ring + roS + tid * 16);                                       \
    sgP += (ADV);                                                         \
    roS += 8192; if (roS == 32768) roS = 0;                               \
  } while (0)

#define PHASE(PP, VMN)                                                    \
  do {                                                                    \
    asm volatile("s_waitcnt vmcnt(" #VMN ")" ::: "memory");               \
    asm volatile("s_barrier" ::: "memory");                               \
    const char* _c = rB + roN;                                            \
    i64x2 bF[4];                                                          \
    _Pragma("unroll") for (int _ni = 0; _ni < 4; ++_ni)                   \
      bF[_ni] = *(const i64x2*)(_c + _ni * 1024);                         \
    asm volatile("s_waitcnt lgkmcnt(0)" ::: "memory");                    \
    __builtin_amdgcn_sched_barrier(0);                                    \
    __builtin_amdgcn_s_setprio(1);                                        \
    _Pragma("unroll") for (int _kl = 0; _kl < 2; ++_kl)                   \
      _Pragma("unroll") for (int _mi = 0; _mi < 4; ++_mi)                 \
        _Pragma("unroll") for (int _ni = 0; _ni < 4; ++_ni)               \
          acc[_mi][_ni] = __builtin_amdgcn_mfma_f32_16x16x32_fp8_fp8(     \
              aR[_mi][(PP)][_kl], bF[_ni][_kl],                           \
              ((PP) == 0 && _kl == 0) ? vzero : acc[_mi][_ni], 0, 0, 0);  \
    __builtin_amdgcn_s_setprio(0);                                        \
    roN += 8192; if (roN == 32768) roN = 0;                               \
  } while (0)

__global__ __launch_bounds__(512, 1) void oim_main_kernel(
    const unsigned char* __restrict__ inf8,
    const unsigned char* __restrict__ bank8,
    float* __restrict__ parts) {
  extern __shared__ char ring[];  // 32768 = 4 slots x 8KB
  const int tid = threadIdx.x;
  const int lane = tid & 63;
  const int wv = tid >> 6;    // 0..7
  const int wrow = wv >> 1;   // 0..3
  const int wcol = wv & 1;    // 0..1
  const int ql = lane & 15;
  const int h = lane >> 4;    // 0..3

  const int bid = blockIdx.x;
  const int sp = bid & 7;     // == XCD id under round-robin dispatch
  const int bm = bid >> 3;    // 0..31 (256-row blocks)
  const int ntiles = (sp < 3) ? 11 : 10;  // 3*11 + 5*10 = 83

  // ---- A fragments -> registers (16 coalesced dwordx4, once) ----
  // aR[mi][kp] = fragment pair (kl0, kl1) for rowblk (bm*16+wrow*4+mi),
  // K64 group kp.
  i64x2 aR[4][4];
  {
    const char* ab =
        (const char*)inf8 + (size_t)(bm * 16 + wrow * 4) * 4096 + lane * 16;
#pragma unroll
    for (int mi = 0; mi < 4; ++mi)
#pragma unroll
      for (int kp = 0; kp < 4; ++kp)
        aR[mi][kp] = *(const i64x2*)(ab + mi * 4096 + kp * 1024);
  }
  const int rowb = bm * 256 + wrow * 64 + h * 4;

  asm volatile("" ::: "memory");  // pin: A-loads precede staging (vmcnt order)

  // staging: 8KB/phase, 1 async16/thread. Slot = [colblk 8 x 1KB][L x 16B];
  // src(pp) = tile + colblk*4096 + pp*1024 + L*16 (colblk = tid>>6, L=tid&63)
  const char* sgT = (const char*)bank8 + (size_t)sp * BTILE;
  // prologue: stage phases 0,1 -> slots 0,1 (2 ops in flight)
#pragma unroll
  for (int p = 0; p < 2; ++p)
    async16(sgT + (tid >> 6) * 4096 + p * 1024 + (tid & 63) * 16,
            ring + p * 8192 + tid * 16);
  const char* sgP = sgT + 2048;  // source k-offset of stage phase 2
  int roS = 16384;               // slot of stage phase 2
  int roN = 0;                   // consume slot

  // per-wave LDS read base (its wcol 64-col strip of 4 colblks)
  const char* rB = ring + wcol * 4096 + lane * 16;

  const f32x4 vzero = {0.f, 0.f, 0.f, 0.f};
  f32x4 acc[4][4];
  float se[4][4];
#pragma unroll
  for (int a = 0; a < 4; ++a)
#pragma unroll
    for (int b = 0; b < 4; ++b) se[a][b] = 0.f;

  for (int t = 0; t < ntiles - 1; ++t) {
    STG(1024);          PHASE(0, 2);
    STG(TSTEP - 3072);  PHASE(1, 2);
    STG(1024);          PHASE(2, 2);
    STG(1024);          PHASE(3, 2);
    // tile epilogue: pure exp2+add (B pre-scaled by rse; pad cols -> +1.0)
#pragma unroll
    for (int mi = 0; mi < 4; ++mi)
#pragma unroll
      for (int ni = 0; ni < 4; ++ni)
#pragma unroll
        for (int r = 0; r < 4; ++r)
          se[mi][r] += __builtin_amdgcn_exp2f(acc[mi][ni][r]);
  }
  // ---- last tile: stage its last two phases, then drain ----
  STG(1024); PHASE(0, 2);
  STG(1024); PHASE(1, 2);
  PHASE(2, 1);
  PHASE(3, 0);
#pragma unroll
  for (int mi = 0; mi < 4; ++mi)
#pragma unroll
    for (int ni = 0; ni < 4; ++ni)
#pragma unroll
      for (int r = 0; r < 4; ++r)
        se[mi][r] += __builtin_amdgcn_exp2f(acc[mi][ni][r]);

  // reduce across the 16 column-lanes (ql) of each row group
#pragma unroll
  for (int mi = 0; mi < 4; ++mi)
#pragma unroll
    for (int r = 0; r < 4; ++r) {
      float v = se[mi][r];
      v += __shfl_xor(v, 1);
      v += __shfl_xor(v, 2);
      v += __shfl_xor(v, 4);
      v += __shfl_xor(v, 8);
      se[mi][r] = v;
    }
  if (ql == 0) {
    const int part = sp * 2 + wcol;  // deterministic partial slot, 0..15
#pragma unroll
    for (int mi = 0; mi < 4; ++mi) {
      f32x4 o = {se[mi][0], se[mi][1], se[mi][2], se[mi][3]};
      *(f32x4*)(parts + (size_t)part * NROWS + rowb + mi * 16) = o;
    }
  }
}

// ---------------------------------------------------------------------------
// reduce1: 32 blocks x 256 threads, one row per thread.
// tot = sum(parts) - PADCOLS; s = ln2*log2(tot) - rowlogit for valid rows.
// ---------------------------------------------------------------------------
__global__ void reduce1_kernel(const float* __restrict__ parts,
                               const float* __restrict__ rowlogit,
                               const int* __restrict__ label,
                               float* __restrict__ blk) {
  const int r = blockIdx.x * 256 + threadIdx.x;
  float s = 0.0f, c = 0.0f;
  if (label[r] != IGNORE_IDX) {
    float tot = 0.0f;
#pragma unroll
    for (int p = 0; p < NPARTS; ++p) tot += parts[p * NROWS + r];
    tot -= (float)PADCOLS;
    s = LN2f * __builtin_log2f(tot) - rowlogit[r];
    c = 1.0f;
  }
#pragma unroll
  for (int m = 1; m < 64; m <<= 1) {
    s += __shfl_xor(s, m);
    c += __shfl_xor(c, m);
  }
  __shared__ float ss[4], sc[4];
  const int wv = threadIdx.x >> 6, lane = threadIdx.x & 63;
  if (lane == 0) { ss[wv] = s; sc[wv] = c; }
  __syncthreads();
  if (threadIdx.x == 0) {
    blk[blockIdx.x * 2 + 0] = ss[0] + ss[1] + ss[2] + ss[3];
    blk[blockIdx.x * 2 + 1] = sc[0] + sc[1] + sc[2] + sc[3];
  }
}

__global__ void reduce2_kernel(const float* __restrict__ blk,
                               float* __restrict__ out) {
  const int lane = threadIdx.x;
  float s = (lane < 32) ? blk[lane * 2 + 0] : 0.0f;
  float c = (lane < 32) ? blk[lane * 2 + 1] : 0.0f;
#pragma unroll
  for (int m = 1; m < 32; m <<= 1) {
    s += __shfl_xor(s, m);
    c += __shfl_xor(c, m);
  }
  if (lane == 0) out[0] = s / fmaxf(c, 1.0f);
}

extern "C" void kernel_launch(void* const* d_in, const int* in_sizes, int n_in,
                              void* d_out, int out_size, void* d_ws,
                              size_t ws_size, hipStream_t stream) {
  const float* inputs = (const float*)d_in[0];
  const int* label = (const int*)d_in[1];
  // d_in[2] = ious (unused by the reference loss)
  const float* lut = (const float*)d_in[3];
  const float* cq = (const float*)d_in[4];
  const float* rel = (const float*)d_in[5];
  float* out = (float*)d_out;
  char* ws = (char*)d_ws;
  if (ws_size < WS_NEED) return;

  unsigned char* inf8 = (unsigned char*)(ws + WS_INF8);
  unsigned char* bank8 = (unsigned char*)(ws + WS_BANK);
  float* parts = (float*)(ws + WS_PARTS);
  float* rowlogit = (float*)(ws + WS_RLOGIT);
  float* blk = (float*)(ws + WS_BLK);

  hipFuncSetAttribute((const void*)oim_main_kernel,
                      hipFuncAttributeMaxDynamicSharedMemorySize, 32768);

  prep_label_kernel<<<dim3(2048), dim3(256), 0, stream>>>(
      inputs, label, lut, cq, rel, inf8, bank8, rowlogit);
  oim_main_kernel<<<dim3(256), dim3(512), 32768, stream>>>(inf8, bank8, parts);
  reduce1_kernel<<<dim3(32), dim3(256), 0, stream>>>(parts, rowlogit, label,
                                                     blk);
  reduce2_kernel<<<dim3(1), dim3(64), 0, stream>>>(blk, out);
}

// Round 20
// 49.540 us; speedup vs baseline: 1.3631x; 1.1000x over previous
//
#include <hip/hip_runtime.h>
#include <stdint.h>

#define NROWS 8192
#define DDIM 256
#define NPIDS 5532
#define NCQ 5000
#define LCOLS 10532            // NPIDS + NCQ
#define IGNORE_IDX 5554
#define NT 83                  // ceil(10532/128)
#define LPAD (NT * 128)        // 10624
#define NSPLIT 8
#define NPARTS (NSPLIT * 2)    // 16 partial slots per row
#define PADCOLS (LPAD - LCOLS) // 92, each contributes exp2(0)=1 exactly
#define BTILE 32768            // fp8 B tile bytes (128 cols x 256 k)
#define TSTEP (NSPLIT * BTILE) // 262144 B between consecutive tiles of a split
#define OIM_SCALE 30.0f
#define LOG2E 1.4426950408889634f
#define LN2f 0.6931471805599453f
#define SA 4.0f                // A pre-scale (folded out of B's scale)

using f32x4 = __attribute__((ext_vector_type(4))) float;
using i64x2 = __attribute__((ext_vector_type(2))) long;
using i32x4 = __attribute__((ext_vector_type(4))) int;

// ws layout (bytes)
#define WS_INF8 0u             // 8192*256*1   = 2,097,152 (frag-order fp8)
#define WS_BANK 2097152u       // 10624*256*1  = 2,719,744 (frag-order, scaled)
#define WS_PARTS 4816896u      // 16*8192*4    = 524,288
#define WS_RLOGIT 5341184u     // 8192*4       = 32,768
#define WS_BLK 5373952u        // 32*2*4       = 256
#define WS_NEED 5374208u

// 4 floats -> 4 OCP e4m3fn bytes via the HW packed converter (RNE, saturate)
__device__ __forceinline__ int pk4(float a, float b, float c, float d) {
  int r = __builtin_amdgcn_cvt_pk_fp8_f32(a, b, 0, false);   // bytes 0,1
  r = __builtin_amdgcn_cvt_pk_fp8_f32(c, d, r, true);        // bytes 2,3
  return r;
}

__device__ __forceinline__ void async16(const void* g, void* l) {
  __builtin_amdgcn_global_load_lds(
      (const __attribute__((address_space(1))) uint32_t*)g,
      (__attribute__((address_space(3))) uint32_t*)l, 16, 0, 0);
}

// ---------------------------------------------------------------------------
// prep + label fused. 2048 blocks x 256 threads.
// Part 1 (label): exact fp32 label logit, one wave per row.
// Part 2 (prep): fp8 e4m3 conversion via v_cvt_pk_fp8_f32 (HW, 2 elem/inst —
// the r19 software converter was ~1.2G branchy VALU ops = ~8us) into MFMA
// fragment-consumption order. 16B granule = one lane's fragment PAIR
// (kl=0 bytes 0-7, kl=1 bytes 8-15) for v_mfma_f32_16x16x32_fp8_fp8:
//   A byte(R,k) = (R>>4)*4096 + (k>>6)*1024 + L*16 + ((k>>5)&1)*8 + (k&7)
//   B byte(C,k) = (C>>7)*32768 + ((C>>4)&7)*4096 + (k>>6)*1024 + L*16 + ...
//   where L = (x&15) | (((k>>3)&3)<<4)
// A scaled by SA=4; B row C scaled by 30*rel[C]*log2e/SA (pad rows = 0).
// ---------------------------------------------------------------------------
__global__ void prep_label_kernel(const float* __restrict__ inputs,
                                  const int* __restrict__ label,
                                  const float* __restrict__ lut,
                                  const float* __restrict__ cq,
                                  const float* __restrict__ rel,
                                  unsigned char* __restrict__ inf8,
                                  unsigned char* __restrict__ bank8,
                                  float* __restrict__ rowlogit) {
  // ---- label logit: one wave per row ----
  {
    const int lane = threadIdx.x & 63;
    const int wvl = threadIdx.x >> 6;
    const int row = blockIdx.x * 4 + wvl;
    const int l = label[row];
    float out = 0.0f;
    if (l != IGNORE_IDX && l >= 0 && l < LCOLS) {
      const float* bk = (l < NPIDS) ? (lut + (size_t)l * DDIM)
                                    : (cq + (size_t)(l - NPIDS) * DDIM);
      f32x4 a = *(const f32x4*)(inputs + (size_t)row * DDIM + lane * 4);
      f32x4 b = *(const f32x4*)(bk + lane * 4);
      float d = a[0] * b[0] + a[1] * b[1] + a[2] * b[2] + a[3] * b[3];
#pragma unroll
      for (int m = 1; m < 64; m <<= 1) d += __shfl_xor(d, m);
      out = OIM_SCALE * rel[l] * d;
    }
    if (lane == 0) rowlogit[row] = out;
  }
  // ---- conversion granules (16B each), grid-stride ----
  const int GIN = NROWS * (DDIM / 16);   // 131072 granules
  const int GBK = LPAD * (DDIM / 16);    // 169984 granules
  const int total = GIN + GBK;
  for (int d = blockIdx.x * blockDim.x + threadIdx.x; d < total;
       d += gridDim.x * blockDim.x) {
    const float* src = nullptr;  // points at 8 floats (kl=0); kl=1 at +32
    unsigned char* dst;
    float scale = 1.0f;
    bool zero = false;
    if (d < GIN) {
      const int rest = d & 255;
      const int L = rest & 63;
      const int R = ((d >> 8) << 4) | (L & 15);
      const int k0 = ((rest >> 6) << 6) | ((L >> 4) << 3);
      src = inputs + (size_t)R * DDIM + k0;
      dst = inf8 + (size_t)d * 16;
      scale = SA;
    } else {
      const int b = d - GIN;
      const int rest = b & 2047;
      const int rest2 = rest & 255;
      const int L = rest2 & 63;
      const int C = ((b >> 11) << 7) | (((rest >> 8) & 7) << 4) | (L & 15);
      const int k0 = ((rest2 >> 6) << 6) | ((L >> 4) << 3);
      dst = bank8 + (size_t)b * 16;
      if (C < NPIDS) src = lut + (size_t)C * DDIM + k0;
      else if (C < LCOLS) src = cq + (size_t)(C - NPIDS) * DDIM + k0;
      else zero = true;
      if (!zero) scale = OIM_SCALE * LOG2E * rel[C] * (1.0f / SA);
    }
    i32x4 o = {0, 0, 0, 0};
    if (!zero) {
      const f32x4* s4 = (const f32x4*)src;
      f32x4 u0 = s4[0], u1 = s4[1];        // kl = 0 (k0 .. k0+7)
      f32x4 w0 = s4[8], w1 = s4[9];        // kl = 1 (k0+32 .. k0+39)
      o[0] = pk4(u0[0] * scale, u0[1] * scale, u0[2] * scale, u0[3] * scale);
      o[1] = pk4(u1[0] * scale, u1[1] * scale, u1[2] * scale, u1[3] * scale);
      o[2] = pk4(w0[0] * scale, w0[1] * scale, w0[2] * scale, w0[3] * scale);
      o[3] = pk4(w1[0] * scale, w1[1] * scale, w1[2] * scale, w1[3] * scale);
    }
    *(i32x4*)dst = o;
  }
}

// ---------------------------------------------------------------------------
// main: fused GEMM + sum-of-exp, r10 structure with fp8 e4m3 operands
// (verbatim round 19 — the measured best). MFMA count/time = bf16 rate but
// every other term halved: ds_read 32 b128/CU/phase, staging 8KB/phase,
// aR 64 VGPR. Ring 4 x 8KB = 32KB LDS. 256 blocks = 1/CU, 512 thr = 8 waves
// (4 wrow x 2 wcol), BM=256, BN=128, K=256 = 4 phases; steady vmcnt(2) +
// one raw s_barrier/phase. sp = bid&7 = XCD id (B slice L2-resident).
// ---------------------------------------------------------------------------
#define STG(ADV)                                                          \
  do {                                                                    \
    async16(sgP + (tid >> 6) * 4096 + (tid & 63) * 16,                    \
            ring + roS + tid * 16);                                       \
    sgP += (ADV);                                                         \
    roS += 8192; if (roS == 32768) roS = 0;                               \
  } while (0)

#define PHASE(PP, VMN)                                                    \
  do {                                                                    \
    asm volatile("s_waitcnt vmcnt(" #VMN ")" ::: "memory");               \
    asm volatile("s_barrier" ::: "memory");                               \
    const char* _c = rB + roN;                                            \
    i64x2 bF[4];                                                          \
    _Pragma("unroll") for (int _ni = 0; _ni < 4; ++_ni)                   \
      bF[_ni] = *(const i64x2*)(_c + _ni * 1024);                         \
    asm volatile("s_waitcnt lgkmcnt(0)" ::: "memory");                    \
    __builtin_amdgcn_sched_barrier(0);                                    \
    __builtin_amdgcn_s_setprio(1);                                        \
    _Pragma("unroll") for (int _kl = 0; _kl < 2; ++_kl)                   \
      _Pragma("unroll") for (int _mi = 0; _mi < 4; ++_mi)                 \
        _Pragma("unroll") for (int _ni = 0; _ni < 4; ++_ni)               \
          acc[_mi][_ni] = __builtin_amdgcn_mfma_f32_16x16x32_fp8_fp8(     \
              aR[_mi][(PP)][_kl], bF[_ni][_kl],                           \
              ((PP) == 0 && _kl == 0) ? vzero : acc[_mi][_ni], 0, 0, 0);  \
    __builtin_amdgcn_s_setprio(0);                                        \
    roN += 8192; if (roN == 32768) roN = 0;                               \
  } while (0)

__global__ __launch_bounds__(512, 1) void oim_main_kernel(
    const unsigned char* __restrict__ inf8,
    const unsigned char* __restrict__ bank8,
    float* __restrict__ parts) {
  extern __shared__ char ring[];  // 32768 = 4 slots x 8KB
  const int tid = threadIdx.x;
  const int lane = tid & 63;
  const int wv = tid >> 6;    // 0..7
  const int wrow = wv >> 1;   // 0..3
  const int wcol = wv & 1;    // 0..1
  const int ql = lane & 15;
  const int h = lane >> 4;    // 0..3

  const int bid = blockIdx.x;
  const int sp = bid & 7;     // == XCD id under round-robin dispatch
  const int bm = bid >> 3;    // 0..31 (256-row blocks)
  const int ntiles = (sp < 3) ? 11 : 10;  // 3*11 + 5*10 = 83

  // ---- A fragments -> registers (16 coalesced dwordx4, once) ----
  i64x2 aR[4][4];
  {
    const char* ab =
        (const char*)inf8 + (size_t)(bm * 16 + wrow * 4) * 4096 + lane * 16;
#pragma unroll
    for (int mi = 0; mi < 4; ++mi)
#pragma unroll
      for (int kp = 0; kp < 4; ++kp)
        aR[mi][kp] = *(const i64x2*)(ab + mi * 4096 + kp * 1024);
  }
  const int rowb = bm * 256 + wrow * 64 + h * 4;

  asm volatile("" ::: "memory");  // pin: A-loads precede staging (vmcnt order)

  // staging: 8KB/phase, 1 async16/thread. Slot = [colblk 8 x 1KB][L x 16B];
  // src(pp) = tile + colblk*4096 + pp*1024 + L*16 (colblk = tid>>6, L=tid&63)
  const char* sgT = (const char*)bank8 + (size_t)sp * BTILE;
  // prologue: stage phases 0,1 -> slots 0,1 (2 ops in flight)
#pragma unroll
  for (int p = 0; p < 2; ++p)
    async16(sgT + (tid >> 6) * 4096 + p * 1024 + (tid & 63) * 16,
            ring + p * 8192 + tid * 16);
  const char* sgP = sgT + 2048;  // source k-offset of stage phase 2
  int roS = 16384;               // slot of stage phase 2
  int roN = 0;                   // consume slot

  // per-wave LDS read base (its wcol 64-col strip of 4 colblks)
  const char* rB = ring + wcol * 4096 + lane * 16;

  const f32x4 vzero = {0.f, 0.f, 0.f, 0.f};
  f32x4 acc[4][4];
  float se[4][4];
#pragma unroll
  for (int a = 0; a < 4; ++a)
#pragma unroll
    for (int b = 0; b < 4; ++b) se[a][b] = 0.f;

  for (int t = 0; t < ntiles - 1; ++t) {
    STG(1024);          PHASE(0, 2);
    STG(TSTEP - 3072);  PHASE(1, 2);
    STG(1024);          PHASE(2, 2);
    STG(1024);          PHASE(3, 2);
    // tile epilogue: pure exp2+add (B pre-scaled by rse; pad cols -> +1.0)
#pragma unroll
    for (int mi = 0; mi < 4; ++mi)
#pragma unroll
      for (int ni = 0; ni < 4; ++ni)
#pragma unroll
        for (int r = 0; r < 4; ++r)
          se[mi][r] += __builtin_amdgcn_exp2f(acc[mi][ni][r]);
  }
  // ---- last tile: stage its last two phases, then drain ----
  STG(1024); PHASE(0, 2);
  STG(1024); PHASE(1, 2);
  PHASE(2, 1);
  PHASE(3, 0);
#pragma unroll
  for (int mi = 0; mi < 4; ++mi)
#pragma unroll
    for (int ni = 0; ni < 4; ++ni)
#pragma unroll
      for (int r = 0; r < 4; ++r)
        se[mi][r] += __builtin_amdgcn_exp2f(acc[mi][ni][r]);

  // reduce across the 16 column-lanes (ql) of each row group
#pragma unroll
  for (int mi = 0; mi < 4; ++mi)
#pragma unroll
    for (int r = 0; r < 4; ++r) {
      float v = se[mi][r];
      v += __shfl_xor(v, 1);
      v += __shfl_xor(v, 2);
      v += __shfl_xor(v, 4);
      v += __shfl_xor(v, 8);
      se[mi][r] = v;
    }
  if (ql == 0) {
    const int part = sp * 2 + wcol;  // deterministic partial slot, 0..15
#pragma unroll
    for (int mi = 0; mi < 4; ++mi) {
      f32x4 o = {se[mi][0], se[mi][1], se[mi][2], se[mi][3]};
      *(f32x4*)(parts + (size_t)part * NROWS + rowb + mi * 16) = o;
    }
  }
}

// ---------------------------------------------------------------------------
// reduce1: 32 blocks x 256 threads, one row per thread.
// tot = sum(parts) - PADCOLS; s = ln2*log2(tot) - rowlogit for valid rows.
// ---------------------------------------------------------------------------
__global__ void reduce1_kernel(const float* __restrict__ parts,
                               const float* __restrict__ rowlogit,
                               const int* __restrict__ label,
                               float* __restrict__ blk) {
  const int r = blockIdx.x * 256 + threadIdx.x;
  float s = 0.0f, c = 0.0f;
  if (label[r] != IGNORE_IDX) {
    float tot = 0.0f;
#pragma unroll
    for (int p = 0; p < NPARTS; ++p) tot += parts[p * NROWS + r];
    tot -= (float)PADCOLS;
    s = LN2f * __builtin_log2f(tot) - rowlogit[r];
    c = 1.0f;
  }
#pragma unroll
  for (int m = 1; m < 64; m <<= 1) {
    s += __shfl_xor(s, m);
    c += __shfl_xor(c, m);
  }
  __shared__ float ss[4], sc[4];
  const int wv = threadIdx.x >> 6, lane = threadIdx.x & 63;
  if (lane == 0) { ss[wv] = s; sc[wv] = c; }
  __syncthreads();
  if (threadIdx.x == 0) {
    blk[blockIdx.x * 2 + 0] = ss[0] + ss[1] + ss[2] + ss[3];
    blk[blockIdx.x * 2 + 1] = sc[0] + sc[1] + sc[2] + sc[3];
  }
}

__global__ void reduce2_kernel(const float* __restrict__ blk,
                               float* __restrict__ out) {
  const int lane = threadIdx.x;
  float s = (lane < 32) ? blk[lane * 2 + 0] : 0.0f;
  float c = (lane < 32) ? blk[lane * 2 + 1] : 0.0f;
#pragma unroll
  for (int m = 1; m < 32; m <<= 1) {
    s += __shfl_xor(s, m);
    c += __shfl_xor(c, m);
  }
  if (lane == 0) out[0] = s / fmaxf(c, 1.0f);
}

extern "C" void kernel_launch(void* const* d_in, const int* in_sizes, int n_in,
                              void* d_out, int out_size, void* d_ws,
                              size_t ws_size, hipStream_t stream) {
  const float* inputs = (const float*)d_in[0];
  const int* label = (const int*)d_in[1];
  // d_in[2] = ious (unused by the reference loss)
  const float* lut = (const float*)d_in[3];
  const float* cq = (const float*)d_in[4];
  const float* rel = (const float*)d_in[5];
  float* out = (float*)d_out;
  char* ws = (char*)d_ws;
  if (ws_size < WS_NEED) return;

  unsigned char* inf8 = (unsigned char*)(ws + WS_INF8);
  unsigned char* bank8 = (unsigned char*)(ws + WS_BANK);
  float* parts = (float*)(ws + WS_PARTS);
  float* rowlogit = (float*)(ws + WS_RLOGIT);
  float* blk = (float*)(ws + WS_BLK);

  hipFuncSetAttribute((const void*)oim_main_kernel,
                      hipFuncAttributeMaxDynamicSharedMemorySize, 32768);

  prep_label_kernel<<<dim3(2048), dim3(256), 0, stream>>>(
      inputs, label, lut, cq, rel, inf8, bank8, rowlogit);
  oim_main_kernel<<<dim3(256), dim3(512), 32768, stream>>>(inf8, bank8, parts);
  reduce1_kernel<<<dim3(32), dim3(256), 0, stream>>>(parts, rowlogit, label,
                                                     blk);
  reduce2_kernel<<<dim3(1), dim3(64), 0, stream>>>(blk, out);
}